// Round 10
// baseline (251.826 us; speedup 1.0000x reference)
//
#include <hip/hip_runtime.h>
#include <stdint.h>

#define BS_   4
#define SEQ_  2048
#define DM_   1024
#define NH_   16
#define DH_   64
#define MTOK_ (BS_*SEQ_)   // 8192

typedef __attribute__((ext_vector_type(8))) short bf16x8;
typedef __attribute__((ext_vector_type(4))) float f32x4;

#define SA_ 0.18033688011112042f   // (1/8) * log2(e)
#define SHIFT_ 16.0f               // fixed softmax shift (exact: softmax is shift-invariant)

__device__ __forceinline__ unsigned short f2bf(float f) {
    union { float f; uint32_t u; } v; v.f = f;
    uint32_t r = v.u + 0x7fffu + ((v.u >> 16) & 1u);
    return (unsigned short)(r >> 16);
}

__device__ __forceinline__ float fexp2(float x) {
#if __has_builtin(__builtin_amdgcn_exp2f)
    return __builtin_amdgcn_exp2f(x);
#else
    return __expf(x * 0.69314718055994531f);
#endif
}

__device__ __forceinline__ uint32_t cvt_pk_bf16(float lo, float hi) {
    uint32_t r;
    asm("v_cvt_pk_bf16_f32 %0, %1, %2" : "=v"(r) : "v"(lo), "v"(hi));
    return r;
}

__device__ __forceinline__ void gload_lds16(const void* g, void* l) {
    __builtin_amdgcn_global_load_lds(
        (const __attribute__((address_space(1))) void*)g,
        (__attribute__((address_space(3))) void*)l, 16, 0, 0);
}

// ---------------- fp32 -> bf16 convert ----------------
__global__ void cvt_kernel(const float* __restrict__ src,
                           unsigned short* __restrict__ dst, int n) {
    int i = (blockIdx.x * blockDim.x + threadIdx.x) * 4;
    const int stride = gridDim.x * blockDim.x * 4;
    for (; i < n; i += stride) {
        float4 v = *(const float4*)(src + i);
        ushort4 o;
        o.x = f2bf(v.x); o.y = f2bf(v.y); o.z = f2bf(v.z); o.w = f2bf(v.w);
        *(ushort4*)(dst + i) = o;
    }
}

// fused 4-matrix weight convert: dst is contiguous (WQ|WK|WV|WO), 1M f32 each
__global__ void cvt4_kernel(const float* __restrict__ s0, const float* __restrict__ s1,
                            const float* __restrict__ s2, const float* __restrict__ s3,
                            unsigned short* __restrict__ dst) {
    const int i = (blockIdx.x * blockDim.x + threadIdx.x) * 4;
    const int mat = i >> 20;
    const int off = i & ((1 << 20) - 1);
    const float* s = (mat == 0) ? s0 : (mat == 1) ? s1 : (mat == 2) ? s2 : s3;
    float4 v = *(const float4*)(s + off);
    ushort4 o;
    o.x = f2bf(v.x); o.y = f2bf(v.y); o.z = f2bf(v.z); o.w = f2bf(v.w);
    *(ushort4*)(dst + i) = o;
}

// ---------------- bt-GEMM: C[M][N] = A[M][K] @ B[N][K]^T ----------------
// MODE 0: QKV projection, scatter epilogue (Q,K as (bh,l,d); V transposed (bh,d,l))
// MODE 1: plain fp32 C + bias (final WO projection)
// XCD-aware swizzle (T1): requires gridDim.x % 8 == 0 (1536 and 512 here).
template<int MODE>
__global__ __launch_bounds__(256) void gemm_bt(
    const unsigned short* __restrict__ A,
    const unsigned short* __restrict__ B,
    int Ndim, int Kdim,
    const float* __restrict__ bias0,
    const float* __restrict__ bias1,
    const float* __restrict__ bias2,
    unsigned short* __restrict__ Qo,
    unsigned short* __restrict__ Ko,
    unsigned short* __restrict__ Vt,
    float* __restrict__ Co)
{
    __shared__ unsigned short As[128 * 32];
    __shared__ unsigned short Bs[128 * 32];

    const int t    = threadIdx.x;
    const int lane = t & 63;
    const int w    = t >> 6;
    const int wr   = w >> 1, wc = w & 1;
    const int g    = lane >> 4, li = lane & 15;

    const int ntile = Ndim >> 7;
    const int per   = gridDim.x >> 3;                      // blocks per XCD chunk
    const int sw    = (blockIdx.x & 7) * per + (blockIdx.x >> 3);
    const int tm = sw / ntile;
    const int tn = sw % ntile;

    const unsigned short* Ab = A + (size_t)tm * 128 * Kdim;
    const unsigned short* Bb = B + (size_t)tn * 128 * Kdim;

    f32x4 acc[4][4];
    const f32x4 zero = {0.f, 0.f, 0.f, 0.f};
    #pragma unroll
    for (int i = 0; i < 4; ++i)
        #pragma unroll
        for (int j = 0; j < 4; ++j)
            acc[i][j] = zero;

    const int s0 = t, s1 = t + 256;
    const int r0 = s0 >> 2, c0 = (s0 & 3) << 3;
    const int r1 = s1 >> 2, c1 = (s1 & 3) << 3;

    for (int k0 = 0; k0 < Kdim; k0 += 32) {
        gload_lds16(Ab + (size_t)r0 * Kdim + k0 + c0, (char*)As + s0 * 16);
        gload_lds16(Ab + (size_t)r1 * Kdim + k0 + c1, (char*)As + s1 * 16);
        gload_lds16(Bb + (size_t)r0 * Kdim + k0 + c0, (char*)Bs + s0 * 16);
        gload_lds16(Bb + (size_t)r1 * Kdim + k0 + c1, (char*)Bs + s1 * 16);
        __syncthreads();

        bf16x8 a[4], b[4];
        #pragma unroll
        for (int mi = 0; mi < 4; ++mi)
            a[mi] = *(const bf16x8*)&As[(wr * 64 + mi * 16 + li) * 32 + g * 8];
        #pragma unroll
        for (int ni = 0; ni < 4; ++ni)
            b[ni] = *(const bf16x8*)&Bs[(wc * 64 + ni * 16 + li) * 32 + g * 8];

        #pragma unroll
        for (int mi = 0; mi < 4; ++mi)
            #pragma unroll
            for (int ni = 0; ni < 4; ++ni)
                acc[mi][ni] = __builtin_amdgcn_mfma_f32_16x16x32_bf16(
                    a[mi], b[ni], acc[mi][ni], 0, 0, 0);
        __syncthreads();
    }

    if constexpr (MODE == 0) {
        #pragma unroll
        for (int mi = 0; mi < 4; ++mi) {
            const int gm0 = tm * 128 + wr * 64 + mi * 16 + g * 4;
            const int bb  = gm0 >> 11;          // / SEQ_
            const int l0  = gm0 & (SEQ_ - 1);
            #pragma unroll
            for (int ni = 0; ni < 4; ++ni) {
                const int gn  = tn * 128 + wc * 64 + ni * 16 + li;
                const int mat = gn >> 10;       // 0=Q 1=K 2=V
                const int c   = gn & (DM_ - 1);
                const int hh  = c >> 6;
                const int dd  = c & (DH_ - 1);
                const float bias = (mat == 0 ? bias0 : (mat == 1 ? bias1 : bias2))[c];
                const f32x4 v = acc[mi][ni];
                if (mat == 2) {
                    // V transposed: Vt[(bh*64 + d)*SEQ + l], 4 consecutive l -> 8B store
                    ushort4 o;
                    o.x = f2bf(v[0] + bias);
                    o.y = f2bf(v[1] + bias);
                    o.z = f2bf(v[2] + bias);
                    o.w = f2bf(v[3] + bias);
                    *(ushort4*)&Vt[((size_t)(bb * NH_ + hh) * DH_ + dd) * SEQ_ + l0] = o;
                } else {
                    unsigned short* dst = (mat == 0) ? Qo : Ko;
                    #pragma unroll
                    for (int r = 0; r < 4; ++r)
                        dst[((size_t)(bb * NH_ + hh) * SEQ_ + l0 + r) * DH_ + dd] =
                            f2bf(v[r] + bias);
                }
            }
        }
    } else {
        #pragma unroll
        for (int mi = 0; mi < 4; ++mi) {
            const int gm0 = tm * 128 + wr * 64 + mi * 16 + g * 4;
            #pragma unroll
            for (int ni = 0; ni < 4; ++ni) {
                const int gn = tn * 128 + wc * 64 + ni * 16 + li;
                const float bias = bias0[gn];
                #pragma unroll
                for (int r = 0; r < 4; ++r)
                    Co[(size_t)(gm0 + r) * Ndim + gn] = acc[mi][ni][r] + bias;
            }
        }
    }
}

// ---------------- flash attention (fixed-shift softmax, 256-row q-tile) --------
// grid: 64 (b*h) x 8 q-tiles of 256 rows. block: 256 thr (4 waves x 64 q-rows).
// Round-8 verified structure; ONLY change: qi loop 2->4 (64 q-rows/wave) to
// amortize the per-iter barrier/staging/latency cost over 2x the MFMA work.
// Swapped S^T = K·Q^T: lane holds S^T[k][q=li] for k = g*4+r+16*ni. P packed
// in-register (cvt_pk) as PV's B-operand with k-slot permutation
// sigma(g,j,kk)=g*4+(j&3)+16*(j>>2)+32*kk, matched on the V^T (A-operand) reads.
// Fixed-shift softmax: P = exp2(S*SA + mask - 16), exact by shift-invariance.
#define KPAD 72   // 144B rows: optimal-spread b128/b64 LDS access
#define NQI 4     // q-frags per wave (64 q-rows)

__global__ __launch_bounds__(256) void attn_kernel(
    const unsigned short* __restrict__ Q,   // (bh, l, d)
    const unsigned short* __restrict__ K,   // (bh, l, d)
    const unsigned short* __restrict__ Vt,  // (bh, d, l)
    const int* __restrict__ kpm,            // (b, SEQ)
    unsigned short* __restrict__ Oo)        // (b, l, dm) merged heads, bf16
{
    __shared__ unsigned short Ks[64 * KPAD];
    __shared__ unsigned short Vs[64 * KPAD];
    __shared__ float maskLds[64];

    const int t    = threadIdx.x;
    const int lane = t & 63;
    const int w    = t >> 6;
    const int g    = lane >> 4, li = lane & 15;

    const int bh = blockIdx.x >> 3;
    const int qt = blockIdx.x & 7;
    const int b  = bh >> 4;
    const int h  = bh & 15;
    const int q0 = qt * 256 + w * 64;

    // Q as B-operand fragments: lane holds Q[q=li][d = kk*32+g*8+j]
    bf16x8 qf[NQI][2];
    #pragma unroll
    for (int qi = 0; qi < NQI; ++qi)
        #pragma unroll
        for (int kk = 0; kk < 2; ++kk)
            qf[qi][kk] = *(const bf16x8*)&Q[((size_t)bh * SEQ_ + q0 + qi * 16 + li) * DH_
                                            + kk * 32 + g * 8];

    f32x4 Oacc[NQI][4];   // O^T fragments: [qi][di], lane: q=li, d=di*16+g*4+r
    const f32x4 zero = {0.f, 0.f, 0.f, 0.f};
    #pragma unroll
    for (int qi = 0; qi < NQI; ++qi)
        #pragma unroll
        for (int di = 0; di < 4; ++di)
            Oacc[qi][di] = zero;

    float lrun[NQI] = {0.f, 0.f, 0.f, 0.f};   // per-lane PARTIAL sums

    const int sr = t >> 3;
    const int sc = (t & 7) * 8;

    bf16x8 kreg0, kreg1, vreg0, vreg1;
    float mreg = 0.f;

    auto load_tile = [&](int kv) {
        kreg0 = *(const bf16x8*)&K[((size_t)bh * SEQ_ + kv + sr) * DH_ + sc];
        kreg1 = *(const bf16x8*)&K[((size_t)bh * SEQ_ + kv + sr + 32) * DH_ + sc];
        vreg0 = *(const bf16x8*)&Vt[((size_t)bh * DH_ + sr) * SEQ_ + kv + sc];
        vreg1 = *(const bf16x8*)&Vt[((size_t)bh * DH_ + sr + 32) * SEQ_ + kv + sc];
        if (t < 64) mreg = (kpm[b * SEQ_ + kv + t] ? -1e9f : 0.0f) - SHIFT_;
    };
    auto store_tile = [&]() {
        *(bf16x8*)&Ks[sr * KPAD + sc] = kreg0;
        *(bf16x8*)&Ks[(sr + 32) * KPAD + sc] = kreg1;
        *(bf16x8*)&Vs[sr * KPAD + sc] = vreg0;
        *(bf16x8*)&Vs[(sr + 32) * KPAD + sc] = vreg1;
        if (t < 64) maskLds[t] = mreg;
    };

    load_tile(0);
    store_tile();

    for (int kv = 0; kv < SEQ_; kv += 64) {
        __syncthreads();
        const bool more = (kv + 64) < SEQ_;
        if (more) load_tile(kv + 64);   // T14: issue early, LDS-write after 2nd barrier

        // mask-shift values for this lane's k slots: k = 16*ni + g*4 + r
        float4 mk[4];
        #pragma unroll
        for (int ni = 0; ni < 4; ++ni)
            mk[ni] = *(const float4*)&maskLds[ni * 16 + g * 4];

        // S^T = K @ Q^T
        f32x4 sacc[NQI][4];   // [qi][ni]
        #pragma unroll
        for (int qi = 0; qi < NQI; ++qi)
            #pragma unroll
            for (int ni = 0; ni < 4; ++ni)
                sacc[qi][ni] = zero;
        __builtin_amdgcn_s_setprio(1);
        #pragma unroll
        for (int ni = 0; ni < 4; ++ni) {
            #pragma unroll
            for (int kk = 0; kk < 2; ++kk) {
                bf16x8 kb = *(const bf16x8*)&Ks[(ni * 16 + li) * KPAD + kk * 32 + g * 8];
                #pragma unroll
                for (int qi = 0; qi < NQI; ++qi)
                    sacc[qi][ni] = __builtin_amdgcn_mfma_f32_16x16x32_bf16(
                        kb, qf[qi][kk], sacc[qi][ni], 0, 0, 0);
            }
        }
        __builtin_amdgcn_s_setprio(0);

        // P = exp2(fma(S, SA, mask-16)); per-lane partial row-sum
        #pragma unroll
        for (int qi = 0; qi < NQI; ++qi) {
            float rs = 0.f;
            #pragma unroll
            for (int ni = 0; ni < 4; ++ni) {
                #pragma unroll
                for (int r = 0; r < 4; ++r) {
                    const float mval = (r == 0) ? mk[ni].x : (r == 1) ? mk[ni].y
                                      : (r == 2) ? mk[ni].z : mk[ni].w;
                    const float p = fexp2(fmaf(sacc[qi][ni][r], SA_, mval));
                    sacc[qi][ni][r] = p;
                    rs += p;
                }
            }
            lrun[qi] += rs;
        }

        // pack P in-register as PV B-operand (k-slot perm: j&3 -> r, j>>2 -> ni-16block)
        bf16x8 pa[NQI][2];
        #pragma unroll
        for (int qi = 0; qi < NQI; ++qi)
            #pragma unroll
            for (int kk = 0; kk < 2; ++kk) {
                union { bf16x8 v; uint32_t w4[4]; } u;
                u.w4[0] = cvt_pk_bf16(sacc[qi][2 * kk][0],     sacc[qi][2 * kk][1]);
                u.w4[1] = cvt_pk_bf16(sacc[qi][2 * kk][2],     sacc[qi][2 * kk][3]);
                u.w4[2] = cvt_pk_bf16(sacc[qi][2 * kk + 1][0], sacc[qi][2 * kk + 1][1]);
                u.w4[3] = cvt_pk_bf16(sacc[qi][2 * kk + 1][2], sacc[qi][2 * kk + 1][3]);
                pa[qi][kk] = u.v;
            }

        // O^T += V^T @ P^T  (V read with matching k-slot permutation)
        __builtin_amdgcn_s_setprio(1);
        #pragma unroll
        for (int di = 0; di < 4; ++di) {
            #pragma unroll
            for (int kk = 0; kk < 2; ++kk) {
                union { bf16x8 v; ushort4 hh[2]; } uv;
                uv.hh[0] = *(const ushort4*)&Vs[(di * 16 + li) * KPAD + kk * 32 + g * 4];
                uv.hh[1] = *(const ushort4*)&Vs[(di * 16 + li) * KPAD + kk * 32 + 16 + g * 4];
                #pragma unroll
                for (int qi = 0; qi < NQI; ++qi)
                    Oacc[qi][di] = __builtin_amdgcn_mfma_f32_16x16x32_bf16(
                        uv.v, pa[qi][kk], Oacc[qi][di], 0, 0, 0);
            }
        }
        __builtin_amdgcn_s_setprio(0);

        __syncthreads();
        if (more) store_tile();
    }

    // epilogue: reduce lrun across g, O/l, packed ushort4 stores (b, l, h*64+d)
    #pragma unroll
    for (int qi = 0; qi < NQI; ++qi) {
        float lt = lrun[qi];
        lt += __shfl_xor(lt, 16);
        lt += __shfl_xor(lt, 32);
        const float inv = 1.0f / lt;
        const int q = q0 + qi * 16 + li;
        #pragma unroll
        for (int di = 0; di < 4; ++di) {
            ushort4 o;
            o.x = f2bf(Oacc[qi][di][0] * inv);
            o.y = f2bf(Oacc[qi][di][1] * inv);
            o.z = f2bf(Oacc[qi][di][2] * inv);
            o.w = f2bf(Oacc[qi][di][3] * inv);
            *(ushort4*)&Oo[((size_t)b * SEQ_ + q) * DM_ + h * 64 + di * 16 + g * 4] = o;
        }
    }
}

extern "C" void kernel_launch(void* const* d_in, const int* in_sizes, int n_in,
                              void* d_out, int out_size, void* d_ws, size_t ws_size,
                              hipStream_t stream) {
    const float* X  = (const float*)d_in[0];
    const int*  kpm = (const int*)d_in[1];
    const float* WQ = (const float*)d_in[2];
    const float* bQ = (const float*)d_in[3];
    const float* WK = (const float*)d_in[4];
    const float* bK = (const float*)d_in[5];
    const float* WV = (const float*)d_in[6];
    const float* bV = (const float*)d_in[7];
    const float* WO = (const float*)d_in[8];
    const float* bO = (const float*)d_in[9];
    float* Out = (float*)d_out;

    char* ws = (char*)d_ws;
    unsigned short* Xb  = (unsigned short*)(ws);                 // 16MB (X bf16; later reused as attn-out)
    unsigned short* Wb  = (unsigned short*)(ws + (16u << 20));   // 6MB  (WQ|WK|WV bf16)
    unsigned short* WOb = (unsigned short*)(ws + (22u << 20));   // 2MB  (contiguous after Wb)
    unsigned short* Qb  = (unsigned short*)(ws + (24u << 20));   // 16MB (bh,l,d)
    unsigned short* Kb  = (unsigned short*)(ws + (40u << 20));   // 16MB (bh,l,d)
    unsigned short* Vtb = (unsigned short*)(ws + (56u << 20));   // 16MB (bh,d,l)
    unsigned short* AOb = Xb;  // alias: Xb dead after QKV GEMM

    cvt_kernel<<<2048, 256, 0, stream>>>(X, Xb, (int)(MTOK_ * DM_));
    cvt4_kernel<<<4096, 256, 0, stream>>>(WQ, WK, WV, WO, Wb);

    gemm_bt<0><<<(MTOK_ / 128) * (3 * DM_ / 128), 256, 0, stream>>>(
        Xb, Wb, 3 * DM_, DM_, bQ, bK, bV, Qb, Kb, Vtb, nullptr);

    attn_kernel<<<BS_ * NH_ * (SEQ_ / 256), 256, 0, stream>>>(Qb, Kb, Vtb, kpm, AOb);

    gemm_bt<1><<<(MTOK_ / 128) * (DM_ / 128), 256, 0, stream>>>(
        AOb, WOb, DM_, DM_, bO, nullptr, nullptr, nullptr, nullptr, nullptr, Out);
}

// Round 11
// 229.124 us; speedup vs baseline: 1.0991x; 1.0991x over previous
//
#include <hip/hip_runtime.h>
#include <stdint.h>

#define BS_   4
#define SEQ_  2048
#define DM_   1024
#define NH_   16
#define DH_   64
#define MTOK_ (BS_*SEQ_)   // 8192

typedef __attribute__((ext_vector_type(8))) short bf16x8;
typedef __attribute__((ext_vector_type(4))) float f32x4;

#define SA_ 0.18033688011112042f   // (1/8) * log2(e)
#define SHIFT_ 16.0f               // fixed softmax shift (exact: softmax is shift-invariant)

__device__ __forceinline__ unsigned short f2bf(float f) {
    union { float f; uint32_t u; } v; v.f = f;
    uint32_t r = v.u + 0x7fffu + ((v.u >> 16) & 1u);
    return (unsigned short)(r >> 16);
}

__device__ __forceinline__ float fexp2(float x) {
#if __has_builtin(__builtin_amdgcn_exp2f)
    return __builtin_amdgcn_exp2f(x);
#else
    return __expf(x * 0.69314718055994531f);
#endif
}

__device__ __forceinline__ uint32_t cvt_pk_bf16(float lo, float hi) {
    uint32_t r;
    asm("v_cvt_pk_bf16_f32 %0, %1, %2" : "=v"(r) : "v"(lo), "v"(hi));
    return r;
}

__device__ __forceinline__ void gload_lds16(const void* g, void* l) {
    __builtin_amdgcn_global_load_lds(
        (const __attribute__((address_space(1))) void*)g,
        (__attribute__((address_space(3))) void*)l, 16, 0, 0);
}

// ---------------- fp32 -> bf16 convert ----------------
__global__ void cvt_kernel(const float* __restrict__ src,
                           unsigned short* __restrict__ dst, int n) {
    int i = (blockIdx.x * blockDim.x + threadIdx.x) * 4;
    const int stride = gridDim.x * blockDim.x * 4;
    for (; i < n; i += stride) {
        float4 v = *(const float4*)(src + i);
        ushort4 o;
        o.x = f2bf(v.x); o.y = f2bf(v.y); o.z = f2bf(v.z); o.w = f2bf(v.w);
        *(ushort4*)(dst + i) = o;
    }
}

// fused 4-matrix weight convert: dst is contiguous (WQ|WK|WV|WO), 1M f32 each
__global__ void cvt4_kernel(const float* __restrict__ s0, const float* __restrict__ s1,
                            const float* __restrict__ s2, const float* __restrict__ s3,
                            unsigned short* __restrict__ dst) {
    const int i = (blockIdx.x * blockDim.x + threadIdx.x) * 4;
    const int mat = i >> 20;
    const int off = i & ((1 << 20) - 1);
    const float* s = (mat == 0) ? s0 : (mat == 1) ? s1 : (mat == 2) ? s2 : s3;
    float4 v = *(const float4*)(s + off);
    ushort4 o;
    o.x = f2bf(v.x); o.y = f2bf(v.y); o.z = f2bf(v.z); o.w = f2bf(v.w);
    *(ushort4*)(dst + i) = o;
}

// ---------------- bt-GEMM: C[M][N] = A[M][K] @ B[N][K]^T ----------------
// MODE 0: QKV projection, scatter epilogue (Q,K as (bh,l,d); V transposed (bh,d,l))
// MODE 1: plain fp32 C + bias (final WO projection)
// XCD-aware swizzle (T1): requires gridDim.x % 8 == 0 (1536 and 512 here).
template<int MODE>
__global__ __launch_bounds__(256) void gemm_bt(
    const unsigned short* __restrict__ A,
    const unsigned short* __restrict__ B,
    int Ndim, int Kdim,
    const float* __restrict__ bias0,
    const float* __restrict__ bias1,
    const float* __restrict__ bias2,
    unsigned short* __restrict__ Qo,
    unsigned short* __restrict__ Ko,
    unsigned short* __restrict__ Vt,
    float* __restrict__ Co)
{
    __shared__ unsigned short As[128 * 32];
    __shared__ unsigned short Bs[128 * 32];

    const int t    = threadIdx.x;
    const int lane = t & 63;
    const int w    = t >> 6;
    const int wr   = w >> 1, wc = w & 1;
    const int g    = lane >> 4, li = lane & 15;

    const int ntile = Ndim >> 7;
    const int per   = gridDim.x >> 3;                      // blocks per XCD chunk
    const int sw    = (blockIdx.x & 7) * per + (blockIdx.x >> 3);
    const int tm = sw / ntile;
    const int tn = sw % ntile;

    const unsigned short* Ab = A + (size_t)tm * 128 * Kdim;
    const unsigned short* Bb = B + (size_t)tn * 128 * Kdim;

    f32x4 acc[4][4];
    const f32x4 zero = {0.f, 0.f, 0.f, 0.f};
    #pragma unroll
    for (int i = 0; i < 4; ++i)
        #pragma unroll
        for (int j = 0; j < 4; ++j)
            acc[i][j] = zero;

    const int s0 = t, s1 = t + 256;
    const int r0 = s0 >> 2, c0 = (s0 & 3) << 3;
    const int r1 = s1 >> 2, c1 = (s1 & 3) << 3;

    for (int k0 = 0; k0 < Kdim; k0 += 32) {
        gload_lds16(Ab + (size_t)r0 * Kdim + k0 + c0, (char*)As + s0 * 16);
        gload_lds16(Ab + (size_t)r1 * Kdim + k0 + c1, (char*)As + s1 * 16);
        gload_lds16(Bb + (size_t)r0 * Kdim + k0 + c0, (char*)Bs + s0 * 16);
        gload_lds16(Bb + (size_t)r1 * Kdim + k0 + c1, (char*)Bs + s1 * 16);
        __syncthreads();

        bf16x8 a[4], b[4];
        #pragma unroll
        for (int mi = 0; mi < 4; ++mi)
            a[mi] = *(const bf16x8*)&As[(wr * 64 + mi * 16 + li) * 32 + g * 8];
        #pragma unroll
        for (int ni = 0; ni < 4; ++ni)
            b[ni] = *(const bf16x8*)&Bs[(wc * 64 + ni * 16 + li) * 32 + g * 8];

        #pragma unroll
        for (int mi = 0; mi < 4; ++mi)
            #pragma unroll
            for (int ni = 0; ni < 4; ++ni)
                acc[mi][ni] = __builtin_amdgcn_mfma_f32_16x16x32_bf16(
                    a[mi], b[ni], acc[mi][ni], 0, 0, 0);
        __syncthreads();
    }

    if constexpr (MODE == 0) {
        #pragma unroll
        for (int mi = 0; mi < 4; ++mi) {
            const int gm0 = tm * 128 + wr * 64 + mi * 16 + g * 4;
            const int bb  = gm0 >> 11;          // / SEQ_
            const int l0  = gm0 & (SEQ_ - 1);
            #pragma unroll
            for (int ni = 0; ni < 4; ++ni) {
                const int gn  = tn * 128 + wc * 64 + ni * 16 + li;
                const int mat = gn >> 10;       // 0=Q 1=K 2=V
                const int c   = gn & (DM_ - 1);
                const int hh  = c >> 6;
                const int dd  = c & (DH_ - 1);
                const float bias = (mat == 0 ? bias0 : (mat == 1 ? bias1 : bias2))[c];
                const f32x4 v = acc[mi][ni];
                if (mat == 2) {
                    // V transposed: Vt[(bh*64 + d)*SEQ + l], 4 consecutive l -> 8B store
                    ushort4 o;
                    o.x = f2bf(v[0] + bias);
                    o.y = f2bf(v[1] + bias);
                    o.z = f2bf(v[2] + bias);
                    o.w = f2bf(v[3] + bias);
                    *(ushort4*)&Vt[((size_t)(bb * NH_ + hh) * DH_ + dd) * SEQ_ + l0] = o;
                } else {
                    unsigned short* dst = (mat == 0) ? Qo : Ko;
                    #pragma unroll
                    for (int r = 0; r < 4; ++r)
                        dst[((size_t)(bb * NH_ + hh) * SEQ_ + l0 + r) * DH_ + dd] =
                            f2bf(v[r] + bias);
                }
            }
        }
    } else {
        #pragma unroll
        for (int mi = 0; mi < 4; ++mi) {
            const int gm0 = tm * 128 + wr * 64 + mi * 16 + g * 4;
            #pragma unroll
            for (int ni = 0; ni < 4; ++ni) {
                const int gn = tn * 128 + wc * 64 + ni * 16 + li;
                const float bias = bias0[gn];
                #pragma unroll
                for (int r = 0; r < 4; ++r)
                    Co[(size_t)(gm0 + r) * Ndim + gn] = acc[mi][ni][r] + bias;
            }
        }
    }
}

// ---------------- flash attention (fixed-shift softmax, KVBLK=128) -------------
// grid: 64 (b*h) x 16 q-tiles of 128 rows (UNCHANGED, 1024 blocks).
// block: 256 thr (4 waves x 32 q-rows).
// KVBLK 64->128: halves barrier count / loop overhead per key; per-key work
// identical. Compute fused per 32-key chunk kc (QK-MFMA -> exp -> pack -> PV)
// to keep live S registers at 16 instead of 64.
// Swapped S^T = K·Q^T: lane holds S^T[k][q=li] for k = g*4+r+16*ni,
// ni = kc*2+nl. P packed in-register (cvt_pk) as PV's B-operand with k-slot
// permutation sigma, matched on the V^T (A-operand) reads (col kc*32+g*4,+16).
// Fixed-shift softmax: P = exp2(S*SA + mask - 16), exact by shift-invariance.
#define KPAD 72    // K row stride (shorts): 144B rows
#define VPAD 136   // V^T row stride (shorts): 272B rows (same 4-step bank walk)
#define KVB 128

__global__ __launch_bounds__(256) void attn_kernel(
    const unsigned short* __restrict__ Q,   // (bh, l, d)
    const unsigned short* __restrict__ K,   // (bh, l, d)
    const unsigned short* __restrict__ Vt,  // (bh, d, l)
    const int* __restrict__ kpm,            // (b, SEQ)
    unsigned short* __restrict__ Oo)        // (b, l, dm) merged heads, bf16
{
    __shared__ unsigned short Ks[KVB * KPAD];   // 18.4 KB
    __shared__ unsigned short Vs[64 * VPAD];    // 17.4 KB
    __shared__ float maskLds[KVB];

    const int t    = threadIdx.x;
    const int lane = t & 63;
    const int w    = t >> 6;
    const int g    = lane >> 4, li = lane & 15;

    const int bh = blockIdx.x >> 4;
    const int qt = blockIdx.x & 15;
    const int b  = bh >> 4;
    const int h  = bh & 15;
    const int q0 = qt * 128 + w * 32;

    // Q as B-operand fragments: lane holds Q[q=li][d = kk*32+g*8+j]
    bf16x8 qf[2][2];
    #pragma unroll
    for (int qi = 0; qi < 2; ++qi)
        #pragma unroll
        for (int kk = 0; kk < 2; ++kk)
            qf[qi][kk] = *(const bf16x8*)&Q[((size_t)bh * SEQ_ + q0 + qi * 16 + li) * DH_
                                            + kk * 32 + g * 8];

    f32x4 Oacc[2][4];   // O^T fragments: [qi][di], lane: q=li, d=di*16+g*4+r
    const f32x4 zero = {0.f, 0.f, 0.f, 0.f};
    #pragma unroll
    for (int qi = 0; qi < 2; ++qi)
        #pragma unroll
        for (int di = 0; di < 4; ++di)
            Oacc[qi][di] = zero;

    float lrun[2] = {0.f, 0.f};   // per-lane PARTIAL sums; reduced in epilogue

    // staging: K = 128 rows x 64 d -> 4 chunks/thread; V^T = 64 d x 128 l -> 4 chunks
    const int krow = t >> 3;          // 0..31
    const int kcol = (t & 7) * 8;     // 0..56
    const int vrow = t >> 4;          // 0..15
    const int vcol = (t & 15) * 8;    // 0..120

    bf16x8 kreg[4], vreg[4];
    float mreg = 0.f;

    auto load_tile = [&](int kv) {
        #pragma unroll
        for (int i = 0; i < 4; ++i)
            kreg[i] = *(const bf16x8*)&K[((size_t)bh * SEQ_ + kv + krow + 32 * i) * DH_ + kcol];
        #pragma unroll
        for (int i = 0; i < 4; ++i)
            vreg[i] = *(const bf16x8*)&Vt[((size_t)bh * DH_ + vrow + 16 * i) * SEQ_ + kv + vcol];
        if (t < KVB) mreg = (kpm[b * SEQ_ + kv + t] ? -1e9f : 0.0f) - SHIFT_;
    };
    auto store_tile = [&]() {
        #pragma unroll
        for (int i = 0; i < 4; ++i)
            *(bf16x8*)&Ks[(krow + 32 * i) * KPAD + kcol] = kreg[i];
        #pragma unroll
        for (int i = 0; i < 4; ++i)
            *(bf16x8*)&Vs[(vrow + 16 * i) * VPAD + vcol] = vreg[i];
        if (t < KVB) maskLds[t] = mreg;
    };

    load_tile(0);
    store_tile();

    for (int kv = 0; kv < SEQ_; kv += KVB) {
        __syncthreads();
        const bool more = (kv + KVB) < SEQ_;
        if (more) load_tile(kv + KVB);   // T14: issue early, LDS-write after 2nd barrier

        #pragma unroll
        for (int kc = 0; kc < 4; ++kc) {
            // mask-shift values for this chunk's k slots: k = kc*32 + nl*16 + g*4 + r
            const float4 mk0 = *(const float4*)&maskLds[kc * 32 + g * 4];
            const float4 mk1 = *(const float4*)&maskLds[kc * 32 + 16 + g * 4];

            // S^T = K @ Q^T for 32 keys
            f32x4 s[2][2];   // [qi][nl]
            s[0][0] = zero; s[0][1] = zero; s[1][0] = zero; s[1][1] = zero;
            __builtin_amdgcn_s_setprio(1);
            #pragma unroll
            for (int nl = 0; nl < 2; ++nl) {
                const int ni = kc * 2 + nl;
                #pragma unroll
                for (int kk = 0; kk < 2; ++kk) {
                    bf16x8 kb = *(const bf16x8*)&Ks[(ni * 16 + li) * KPAD + kk * 32 + g * 8];
                    s[0][nl] = __builtin_amdgcn_mfma_f32_16x16x32_bf16(
                        kb, qf[0][kk], s[0][nl], 0, 0, 0);
                    s[1][nl] = __builtin_amdgcn_mfma_f32_16x16x32_bf16(
                        kb, qf[1][kk], s[1][nl], 0, 0, 0);
                }
            }
            __builtin_amdgcn_s_setprio(0);

            // P = exp2(fma(S, SA, mask-16)); per-lane partial row-sum
            #pragma unroll
            for (int qi = 0; qi < 2; ++qi) {
                float rs = 0.f;
                #pragma unroll
                for (int r = 0; r < 4; ++r) {
                    const float m0 = (r == 0) ? mk0.x : (r == 1) ? mk0.y
                                    : (r == 2) ? mk0.z : mk0.w;
                    const float p0 = fexp2(fmaf(s[qi][0][r], SA_, m0));
                    s[qi][0][r] = p0;
                    rs += p0;
                    const float m1 = (r == 0) ? mk1.x : (r == 1) ? mk1.y
                                    : (r == 2) ? mk1.z : mk1.w;
                    const float p1 = fexp2(fmaf(s[qi][1][r], SA_, m1));
                    s[qi][1][r] = p1;
                    rs += p1;
                }
                lrun[qi] += rs;
            }

            // pack P in-register as PV B-operand (k-slot perm sigma)
            bf16x8 pv[2];
            #pragma unroll
            for (int qi = 0; qi < 2; ++qi) {
                union { bf16x8 v; uint32_t w4[4]; } u;
                u.w4[0] = cvt_pk_bf16(s[qi][0][0], s[qi][0][1]);
                u.w4[1] = cvt_pk_bf16(s[qi][0][2], s[qi][0][3]);
                u.w4[2] = cvt_pk_bf16(s[qi][1][0], s[qi][1][1]);
                u.w4[3] = cvt_pk_bf16(s[qi][1][2], s[qi][1][3]);
                pv[qi] = u.v;
            }

            // O^T += V^T @ P^T  (V read with matching k-slot permutation)
            __builtin_amdgcn_s_setprio(1);
            #pragma unroll
            for (int di = 0; di < 4; ++di) {
                union { bf16x8 v; ushort4 hh[2]; } uv;
                uv.hh[0] = *(const ushort4*)&Vs[(di * 16 + li) * VPAD + kc * 32 + g * 4];
                uv.hh[1] = *(const ushort4*)&Vs[(di * 16 + li) * VPAD + kc * 32 + 16 + g * 4];
                Oacc[0][di] = __builtin_amdgcn_mfma_f32_16x16x32_bf16(
                    uv.v, pv[0], Oacc[0][di], 0, 0, 0);
                Oacc[1][di] = __builtin_amdgcn_mfma_f32_16x16x32_bf16(
                    uv.v, pv[1], Oacc[1][di], 0, 0, 0);
            }
            __builtin_amdgcn_s_setprio(0);
        }

        __syncthreads();
        if (more) store_tile();
    }

    // epilogue: reduce lrun across g, O/l, packed ushort4 stores (b, l, h*64+d)
    #pragma unroll
    for (int qi = 0; qi < 2; ++qi) {
        float lt = lrun[qi];
        lt += __shfl_xor(lt, 16);
        lt += __shfl_xor(lt, 32);
        const float inv = 1.0f / lt;
        const int q = q0 + qi * 16 + li;
        #pragma unroll
        for (int di = 0; di < 4; ++di) {
            ushort4 o;
            o.x = f2bf(Oacc[qi][di][0] * inv);
            o.y = f2bf(Oacc[qi][di][1] * inv);
            o.z = f2bf(Oacc[qi][di][2] * inv);
            o.w = f2bf(Oacc[qi][di][3] * inv);
            *(ushort4*)&Oo[((size_t)b * SEQ_ + q) * DM_ + h * 64 + di * 16 + g * 4] = o;
        }
    }
}

extern "C" void kernel_launch(void* const* d_in, const int* in_sizes, int n_in,
                              void* d_out, int out_size, void* d_ws, size_t ws_size,
                              hipStream_t stream) {
    const float* X  = (const float*)d_in[0];
    const int*  kpm = (const int*)d_in[1];
    const float* WQ = (const float*)d_in[2];
    const float* bQ = (const float*)d_in[3];
    const float* WK = (const float*)d_in[4];
    const float* bK = (const float*)d_in[5];
    const float* WV = (const float*)d_in[6];
    const float* bV = (const float*)d_in[7];
    const float* WO = (const float*)d_in[8];
    const float* bO = (const float*)d_in[9];
    float* Out = (float*)d_out;

    char* ws = (char*)d_ws;
    unsigned short* Xb  = (unsigned short*)(ws);                 // 16MB (X bf16; later reused as attn-out)
    unsigned short* Wb  = (unsigned short*)(ws + (16u << 20));   // 6MB  (WQ|WK|WV bf16)
    unsigned short* WOb = (unsigned short*)(ws + (22u << 20));   // 2MB  (contiguous after Wb)
    unsigned short* Qb  = (unsigned short*)(ws + (24u << 20));   // 16MB (bh,l,d)
    unsigned short* Kb  = (unsigned short*)(ws + (40u << 20));   // 16MB (bh,l,d)
    unsigned short* Vtb = (unsigned short*)(ws + (56u << 20));   // 16MB (bh,d,l)
    unsigned short* AOb = Xb;  // alias: Xb dead after QKV GEMM

    cvt_kernel<<<2048, 256, 0, stream>>>(X, Xb, (int)(MTOK_ * DM_));
    cvt4_kernel<<<4096, 256, 0, stream>>>(WQ, WK, WV, WO, Wb);

    gemm_bt<0><<<(MTOK_ / 128) * (3 * DM_ / 128), 256, 0, stream>>>(
        Xb, Wb, 3 * DM_, DM_, bQ, bK, bV, Qb, Kb, Vtb, nullptr);

    attn_kernel<<<BS_ * NH_ * (SEQ_ / 128), 256, 0, stream>>>(Qb, Kb, Vtb, kpm, AOb);

    gemm_bt<1><<<(MTOK_ / 128) * (DM_ / 128), 256, 0, stream>>>(
        AOb, WOb, DM_, DM_, bO, nullptr, nullptr, nullptr, nullptr, nullptr, Out);
}

// Round 12
// 221.984 us; speedup vs baseline: 1.1344x; 1.0322x over previous
//
#include <hip/hip_runtime.h>
#include <stdint.h>

#define BS_   4
#define SEQ_  2048
#define DM_   1024
#define NH_   16
#define DH_   64
#define MTOK_ (BS_*SEQ_)   // 8192

typedef __attribute__((ext_vector_type(8))) short bf16x8;
typedef __attribute__((ext_vector_type(4))) float f32x4;

#define SA_ 0.18033688011112042f   // (1/8) * log2(e)
#define SHIFT_ 16.0f               // fixed softmax shift (exact: softmax is shift-invariant)

__device__ __forceinline__ unsigned short f2bf(float f) {
    union { float f; uint32_t u; } v; v.f = f;
    uint32_t r = v.u + 0x7fffu + ((v.u >> 16) & 1u);
    return (unsigned short)(r >> 16);
}

__device__ __forceinline__ float fexp2(float x) {
#if __has_builtin(__builtin_amdgcn_exp2f)
    return __builtin_amdgcn_exp2f(x);
#else
    return __expf(x * 0.69314718055994531f);
#endif
}

__device__ __forceinline__ uint32_t cvt_pk_bf16(float lo, float hi) {
    uint32_t r;
    asm("v_cvt_pk_bf16_f32 %0, %1, %2" : "=v"(r) : "v"(lo), "v"(hi));
    return r;
}

__device__ __forceinline__ void gload_lds16(const void* g, void* l) {
    __builtin_amdgcn_global_load_lds(
        (const __attribute__((address_space(1))) void*)g,
        (__attribute__((address_space(3))) void*)l, 16, 0, 0);
}

// ---------------- fp32 -> bf16 convert ----------------
__global__ void cvt_kernel(const float* __restrict__ src,
                           unsigned short* __restrict__ dst, int n) {
    int i = (blockIdx.x * blockDim.x + threadIdx.x) * 4;
    const int stride = gridDim.x * blockDim.x * 4;
    for (; i < n; i += stride) {
        float4 v = *(const float4*)(src + i);
        ushort4 o;
        o.x = f2bf(v.x); o.y = f2bf(v.y); o.z = f2bf(v.z); o.w = f2bf(v.w);
        *(ushort4*)(dst + i) = o;
    }
}

// fused 4-matrix weight convert: dst is contiguous (WQ|WK|WV|WO), 1M f32 each
__global__ void cvt4_kernel(const float* __restrict__ s0, const float* __restrict__ s1,
                            const float* __restrict__ s2, const float* __restrict__ s3,
                            unsigned short* __restrict__ dst) {
    const int i = (blockIdx.x * blockDim.x + threadIdx.x) * 4;
    const int mat = i >> 20;
    const int off = i & ((1 << 20) - 1);
    const float* s = (mat == 0) ? s0 : (mat == 1) ? s1 : (mat == 2) ? s2 : s3;
    float4 v = *(const float4*)(s + off);
    ushort4 o;
    o.x = f2bf(v.x); o.y = f2bf(v.y); o.z = f2bf(v.z); o.w = f2bf(v.w);
    *(ushort4*)(dst + i) = o;
}

// ---------------- bt-GEMM: C[M][N] = A[M][K] @ B[N][K]^T ----------------
// MODE 0: QKV projection, scatter epilogue (Q,K as (bh,l,d); V transposed (bh,d,l)
//         with sigma-permutation within each 32-element l-block so attention PV
//         A-fragments are single b128 reads).
// MODE 1: plain fp32 C + bias (final WO projection)
// XCD-aware swizzle (T1): requires gridDim.x % 8 == 0 (1536 and 512 here).
template<int MODE>
__global__ __launch_bounds__(256) void gemm_bt(
    const unsigned short* __restrict__ A,
    const unsigned short* __restrict__ B,
    int Ndim, int Kdim,
    const float* __restrict__ bias0,
    const float* __restrict__ bias1,
    const float* __restrict__ bias2,
    unsigned short* __restrict__ Qo,
    unsigned short* __restrict__ Ko,
    unsigned short* __restrict__ Vt,
    float* __restrict__ Co)
{
    __shared__ unsigned short As[128 * 32];
    __shared__ unsigned short Bs[128 * 32];

    const int t    = threadIdx.x;
    const int lane = t & 63;
    const int w    = t >> 6;
    const int wr   = w >> 1, wc = w & 1;
    const int g    = lane >> 4, li = lane & 15;

    const int ntile = Ndim >> 7;
    const int per   = gridDim.x >> 3;                      // blocks per XCD chunk
    const int sw    = (blockIdx.x & 7) * per + (blockIdx.x >> 3);
    const int tm = sw / ntile;
    const int tn = sw % ntile;

    const unsigned short* Ab = A + (size_t)tm * 128 * Kdim;
    const unsigned short* Bb = B + (size_t)tn * 128 * Kdim;

    f32x4 acc[4][4];
    const f32x4 zero = {0.f, 0.f, 0.f, 0.f};
    #pragma unroll
    for (int i = 0; i < 4; ++i)
        #pragma unroll
        for (int j = 0; j < 4; ++j)
            acc[i][j] = zero;

    const int s0 = t, s1 = t + 256;
    const int r0 = s0 >> 2, c0 = (s0 & 3) << 3;
    const int r1 = s1 >> 2, c1 = (s1 & 3) << 3;

    for (int k0 = 0; k0 < Kdim; k0 += 32) {
        gload_lds16(Ab + (size_t)r0 * Kdim + k0 + c0, (char*)As + s0 * 16);
        gload_lds16(Ab + (size_t)r1 * Kdim + k0 + c1, (char*)As + s1 * 16);
        gload_lds16(Bb + (size_t)r0 * Kdim + k0 + c0, (char*)Bs + s0 * 16);
        gload_lds16(Bb + (size_t)r1 * Kdim + k0 + c1, (char*)Bs + s1 * 16);
        __syncthreads();

        bf16x8 a[4], b[4];
        #pragma unroll
        for (int mi = 0; mi < 4; ++mi)
            a[mi] = *(const bf16x8*)&As[(wr * 64 + mi * 16 + li) * 32 + g * 8];
        #pragma unroll
        for (int ni = 0; ni < 4; ++ni)
            b[ni] = *(const bf16x8*)&Bs[(wc * 64 + ni * 16 + li) * 32 + g * 8];

        #pragma unroll
        for (int mi = 0; mi < 4; ++mi)
            #pragma unroll
            for (int ni = 0; ni < 4; ++ni)
                acc[mi][ni] = __builtin_amdgcn_mfma_f32_16x16x32_bf16(
                    a[mi], b[ni], acc[mi][ni], 0, 0, 0);
        __syncthreads();
    }

    if constexpr (MODE == 0) {
        #pragma unroll
        for (int mi = 0; mi < 4; ++mi) {
            const int gm0 = tm * 128 + wr * 64 + mi * 16 + g * 4;
            const int bb  = gm0 >> 11;          // / SEQ_
            const int l0  = gm0 & (SEQ_ - 1);
            #pragma unroll
            for (int ni = 0; ni < 4; ++ni) {
                const int gn  = tn * 128 + wc * 64 + ni * 16 + li;
                const int mat = gn >> 10;       // 0=Q 1=K 2=V
                const int c   = gn & (DM_ - 1);
                const int hh  = c >> 6;
                const int dd  = c & (DH_ - 1);
                const float bias = (mat == 0 ? bias0 : (mat == 1 ? bias1 : bias2))[c];
                const f32x4 v = acc[mi][ni];
                if (mat == 2) {
                    // V transposed + sigma-permuted within each 32-block of l:
                    // p = ((l&12)<<1) | (l&3) | ((l&16)>>2); l0 has bits1:0 == 0,
                    // so the 4 consecutive values stay contiguous at lp.
                    const int lp = (l0 & ~31) | ((l0 & 12) << 1) | ((l0 & 16) >> 2);
                    ushort4 o;
                    o.x = f2bf(v[0] + bias);
                    o.y = f2bf(v[1] + bias);
                    o.z = f2bf(v[2] + bias);
                    o.w = f2bf(v[3] + bias);
                    *(ushort4*)&Vt[((size_t)(bb * NH_ + hh) * DH_ + dd) * SEQ_ + lp] = o;
                } else {
                    unsigned short* dst = (mat == 0) ? Qo : Ko;
                    #pragma unroll
                    for (int r = 0; r < 4; ++r)
                        dst[((size_t)(bb * NH_ + hh) * SEQ_ + l0 + r) * DH_ + dd] =
                            f2bf(v[r] + bias);
                }
            }
        }
    } else {
        #pragma unroll
        for (int mi = 0; mi < 4; ++mi) {
            const int gm0 = tm * 128 + wr * 64 + mi * 16 + g * 4;
            #pragma unroll
            for (int ni = 0; ni < 4; ++ni) {
                const int gn = tn * 128 + wc * 64 + ni * 16 + li;
                const float bias = bias0[gn];
                #pragma unroll
                for (int r = 0; r < 4; ++r)
                    Co[(size_t)(gm0 + r) * Ndim + gn] = acc[mi][ni][r] + bias;
            }
        }
    }
}

// ---------------- flash attention (round-8 verified base + 2 deltas) -----------
// grid: 1024 blocks, HEAD-LOCAL XCD swizzle: all 16 q-tiles of one head share
// bid%8 (one XCD) -> that head's K/V (512KB) stays L2-resident (8 heads = 4MB/XCD).
// block: 256 thr (4 waves x 32 q-rows), KVBLK=64.
// Swapped S^T = K·Q^T: lane holds S^T[k][q=li] for k = g*4+r+16*ni. P packed
// in-register (cvt_pk) as PV's B-operand with k-slot permutation
// sigma(g,j,kk)=g*4+(j&3)+16*(j>>2)+32*kk. V arrives pre-sigma-permuted from the
// GEMM epilogue -> PV A-fragment is a SINGLE ds_read_b128 (was 2x b64).
// Fixed-shift softmax: P = exp2(S*SA + mask - 16), exact by shift-invariance.
#define KPAD 72   // 144B rows: optimal-spread b128 LDS access

__global__ __launch_bounds__(256) void attn_kernel(
    const unsigned short* __restrict__ Q,   // (bh, l, d)
    const unsigned short* __restrict__ K,   // (bh, l, d)
    const unsigned short* __restrict__ Vt,  // (bh, d, l) sigma-permuted
    const int* __restrict__ kpm,            // (b, SEQ)
    unsigned short* __restrict__ Oo)        // (b, l, dm) merged heads, bf16
{
    __shared__ unsigned short Ks[64 * KPAD];
    __shared__ unsigned short Vs[64 * KPAD];
    __shared__ float maskLds[64];

    const int t    = threadIdx.x;
    const int lane = t & 63;
    const int w    = t >> 6;
    const int g    = lane >> 4, li = lane & 15;

    // head-local XCD swizzle: bid = (bh&7) + 8*((bh>>3)*16 + qt)  [bijective]
    const int bh = ((blockIdx.x >> 7) << 3) + (blockIdx.x & 7);
    const int qt = (blockIdx.x >> 3) & 15;
    const int b  = bh >> 4;
    const int h  = bh & 15;
    const int q0 = qt * 128 + w * 32;

    // Q as B-operand fragments: lane holds Q[q=li][d = kk*32+g*8+j]
    bf16x8 qf[2][2];
    #pragma unroll
    for (int qi = 0; qi < 2; ++qi)
        #pragma unroll
        for (int kk = 0; kk < 2; ++kk)
            qf[qi][kk] = *(const bf16x8*)&Q[((size_t)bh * SEQ_ + q0 + qi * 16 + li) * DH_
                                            + kk * 32 + g * 8];

    f32x4 Oacc[2][4];   // O^T fragments: [qi][di], lane: q=li, d=di*16+g*4+r
    const f32x4 zero = {0.f, 0.f, 0.f, 0.f};
    #pragma unroll
    for (int qi = 0; qi < 2; ++qi)
        #pragma unroll
        for (int di = 0; di < 4; ++di)
            Oacc[qi][di] = zero;

    float lrun[2] = {0.f, 0.f};   // per-lane PARTIAL sums; reduced in epilogue

    const int sr = t >> 3;
    const int sc = (t & 7) * 8;

    bf16x8 kreg0, kreg1, vreg0, vreg1;
    float mreg = 0.f;

    auto load_tile = [&](int kv) {
        kreg0 = *(const bf16x8*)&K[((size_t)bh * SEQ_ + kv + sr) * DH_ + sc];
        kreg1 = *(const bf16x8*)&K[((size_t)bh * SEQ_ + kv + sr + 32) * DH_ + sc];
        vreg0 = *(const bf16x8*)&Vt[((size_t)bh * DH_ + sr) * SEQ_ + kv + sc];
        vreg1 = *(const bf16x8*)&Vt[((size_t)bh * DH_ + sr + 32) * SEQ_ + kv + sc];
        if (t < 64) mreg = (kpm[b * SEQ_ + kv + t] ? -1e9f : 0.0f) - SHIFT_;
    };
    auto store_tile = [&]() {
        *(bf16x8*)&Ks[sr * KPAD + sc] = kreg0;
        *(bf16x8*)&Ks[(sr + 32) * KPAD + sc] = kreg1;
        *(bf16x8*)&Vs[sr * KPAD + sc] = vreg0;
        *(bf16x8*)&Vs[(sr + 32) * KPAD + sc] = vreg1;
        if (t < 64) maskLds[t] = mreg;
    };

    load_tile(0);
    store_tile();

    for (int kv = 0; kv < SEQ_; kv += 64) {
        __syncthreads();
        const bool more = (kv + 64) < SEQ_;
        if (more) load_tile(kv + 64);   // T14: issue early, LDS-write after 2nd barrier

        // mask-shift values for this lane's k slots: k = 16*ni + g*4 + r
        float4 mk[4];
        #pragma unroll
        for (int ni = 0; ni < 4; ++ni)
            mk[ni] = *(const float4*)&maskLds[ni * 16 + g * 4];

        // S^T = K @ Q^T
        f32x4 sacc[2][4];   // [qi][ni]
        #pragma unroll
        for (int qi = 0; qi < 2; ++qi)
            #pragma unroll
            for (int ni = 0; ni < 4; ++ni)
                sacc[qi][ni] = zero;
        __builtin_amdgcn_s_setprio(1);
        #pragma unroll
        for (int ni = 0; ni < 4; ++ni) {
            #pragma unroll
            for (int kk = 0; kk < 2; ++kk) {
                bf16x8 kb = *(const bf16x8*)&Ks[(ni * 16 + li) * KPAD + kk * 32 + g * 8];
                sacc[0][ni] = __builtin_amdgcn_mfma_f32_16x16x32_bf16(
                    kb, qf[0][kk], sacc[0][ni], 0, 0, 0);
                sacc[1][ni] = __builtin_amdgcn_mfma_f32_16x16x32_bf16(
                    kb, qf[1][kk], sacc[1][ni], 0, 0, 0);
            }
        }
        __builtin_amdgcn_s_setprio(0);

        // P = exp2(fma(S, SA, mask-16)); per-lane partial row-sum
        #pragma unroll
        for (int qi = 0; qi < 2; ++qi) {
            float rs = 0.f;
            #pragma unroll
            for (int ni = 0; ni < 4; ++ni) {
                #pragma unroll
                for (int r = 0; r < 4; ++r) {
                    const float mval = (r == 0) ? mk[ni].x : (r == 1) ? mk[ni].y
                                      : (r == 2) ? mk[ni].z : mk[ni].w;
                    const float p = fexp2(fmaf(sacc[qi][ni][r], SA_, mval));
                    sacc[qi][ni][r] = p;
                    rs += p;
                }
            }
            lrun[qi] += rs;
        }

        // pack P in-register as PV B-operand (k-slot perm: j&3 -> r, j>>2 -> ni-16block)
        bf16x8 pa[2][2];
        #pragma unroll
        for (int qi = 0; qi < 2; ++qi)
            #pragma unroll
            for (int kk = 0; kk < 2; ++kk) {
                union { bf16x8 v; uint32_t w4[4]; } u;
                u.w4[0] = cvt_pk_bf16(sacc[qi][2 * kk][0],     sacc[qi][2 * kk][1]);
                u.w4[1] = cvt_pk_bf16(sacc[qi][2 * kk][2],     sacc[qi][2 * kk][3]);
                u.w4[2] = cvt_pk_bf16(sacc[qi][2 * kk + 1][0], sacc[qi][2 * kk + 1][1]);
                u.w4[3] = cvt_pk_bf16(sacc[qi][2 * kk + 1][2], sacc[qi][2 * kk + 1][3]);
                pa[qi][kk] = u.v;
            }

        // O^T += V^T @ P^T  (V pre-sigma-permuted -> single b128 per fragment)
        __builtin_amdgcn_s_setprio(1);
        #pragma unroll
        for (int di = 0; di < 4; ++di) {
            #pragma unroll
            for (int kk = 0; kk < 2; ++kk) {
                bf16x8 vb = *(const bf16x8*)&Vs[(di * 16 + li) * KPAD + kk * 32 + g * 8];
                Oacc[0][di] = __builtin_amdgcn_mfma_f32_16x16x32_bf16(
                    vb, pa[0][kk], Oacc[0][di], 0, 0, 0);
                Oacc[1][di] = __builtin_amdgcn_mfma_f32_16x16x32_bf16(
                    vb, pa[1][kk], Oacc[1][di], 0, 0, 0);
            }
        }
        __builtin_amdgcn_s_setprio(0);

        __syncthreads();
        if (more) store_tile();
    }

    // epilogue: reduce lrun across g, O/l, packed ushort4 stores (b, l, h*64+d)
    #pragma unroll
    for (int qi = 0; qi < 2; ++qi) {
        float lt = lrun[qi];
        lt += __shfl_xor(lt, 16);
        lt += __shfl_xor(lt, 32);
        const float inv = 1.0f / lt;
        const int q = q0 + qi * 16 + li;
        #pragma unroll
        for (int di = 0; di < 4; ++di) {
            ushort4 o;
            o.x = f2bf(Oacc[qi][di][0] * inv);
            o.y = f2bf(Oacc[qi][di][1] * inv);
            o.z = f2bf(Oacc[qi][di][2] * inv);
            o.w = f2bf(Oacc[qi][di][3] * inv);
            *(ushort4*)&Oo[((size_t)b * SEQ_ + q) * DM_ + h * 64 + di * 16 + g * 4] = o;
        }
    }
}

extern "C" void kernel_launch(void* const* d_in, const int* in_sizes, int n_in,
                              void* d_out, int out_size, void* d_ws, size_t ws_size,
                              hipStream_t stream) {
    const float* X  = (const float*)d_in[0];
    const int*  kpm = (const int*)d_in[1];
    const float* WQ = (const float*)d_in[2];
    const float* bQ = (const float*)d_in[3];
    const float* WK = (const float*)d_in[4];
    const float* bK = (const float*)d_in[5];
    const float* WV = (const float*)d_in[6];
    const float* bV = (const float*)d_in[7];
    const float* WO = (const float*)d_in[8];
    const float* bO = (const float*)d_in[9];
    float* Out = (float*)d_out;

    char* ws = (char*)d_ws;
    unsigned short* Xb  = (unsigned short*)(ws);                 // 16MB (X bf16; later reused as attn-out)
    unsigned short* Wb  = (unsigned short*)(ws + (16u << 20));   // 6MB  (WQ|WK|WV bf16)
    unsigned short* WOb = (unsigned short*)(ws + (22u << 20));   // 2MB  (contiguous after Wb)
    unsigned short* Qb  = (unsigned short*)(ws + (24u << 20));   // 16MB (bh,l,d)
    unsigned short* Kb  = (unsigned short*)(ws + (40u << 20));   // 16MB (bh,l,d)
    unsigned short* Vtb = (unsigned short*)(ws + (56u << 20));   // 16MB (bh,d,l) sigma-permuted
    unsigned short* AOb = Xb;  // alias: Xb dead after QKV GEMM

    cvt_kernel<<<2048, 256, 0, stream>>>(X, Xb, (int)(MTOK_ * DM_));
    cvt4_kernel<<<4096, 256, 0, stream>>>(WQ, WK, WV, WO, Wb);

    gemm_bt<0><<<(MTOK_ / 128) * (3 * DM_ / 128), 256, 0, stream>>>(
        Xb, Wb, 3 * DM_, DM_, bQ, bK, bV, Qb, Kb, Vtb, nullptr);

    attn_kernel<<<BS_ * NH_ * (SEQ_ / 128), 256, 0, stream>>>(Qb, Kb, Vtb, kpm, AOb);

    gemm_bt<1><<<(MTOK_ / 128) * (DM_ / 128), 256, 0, stream>>>(
        AOb, WOb, DM_, DM_, bO, nullptr, nullptr, nullptr, nullptr, nullptr, Out);
}